// Round 4
// baseline (840.290 us; speedup 1.0000x reference)
//
#include <hip/hip_runtime.h>
#include <hip/hip_bf16.h>

// TransNormer: causal linear attention, B=2 N=2048 D=2048 H=16 I=1 K=V=128.
// Precision strategy: every tensor on a matmul path is stored as split bf16
// (hi + lo) planes; every contraction runs 3 MFMA passes
// (hi*hi + hi*lo + lo*hi) with fp32 accumulation => effective fp32 GEMMs.

typedef short          bf16x8 __attribute__((ext_vector_type(8)));
typedef unsigned short u16x8  __attribute__((ext_vector_type(8)));
typedef unsigned short u16x4  __attribute__((ext_vector_type(4)));
typedef float          f32x4  __attribute__((ext_vector_type(4)));

#define DEV static __device__ __forceinline__

DEV unsigned short f2bf(float f) {  // RNE fp32 -> bf16 bits
  union { float f; unsigned u; } v; v.f = f;
  unsigned r = v.u + 0x7fffu + ((v.u >> 16) & 1u);
  return (unsigned short)(r >> 16);
}
DEV float bf2f(unsigned short h) {
  union { unsigned u; float f; } v; v.u = ((unsigned)h) << 16; return v.f;
}
struct bfpair { unsigned short h, l; };
DEV bfpair split2(float x) {
  bfpair p; p.h = f2bf(x); p.l = f2bf(x - bf2f(p.h)); return p;
}

// XOR swizzle of byte bits 4-6 (bank-group spread for b128 reads + b16 writes)
DEV int swzx(int row) { return (((row & 7) ^ ((row >> 3) & 7)) << 4); }

// ---------------- cast fp32 -> bf16 hi/lo planes ----------------
__global__ void k_split(const float* __restrict__ in, unsigned short* __restrict__ hi,
                        unsigned short* __restrict__ lo, int n) {
  int i = (blockIdx.x * blockDim.x + threadIdx.x) * 4;
  int stride = gridDim.x * blockDim.x * 4;
  for (; i < n; i += stride) {
    float4 v = *reinterpret_cast<const float4*>(in + i);
    bfpair a = split2(v.x), b = split2(v.y), c = split2(v.z), d = split2(v.w);
    u16x4 h, l;
    h[0] = a.h; h[1] = b.h; h[2] = c.h; h[3] = d.h;
    l[0] = a.l; l[1] = b.l; l[2] = c.l; l[3] = d.l;
    *reinterpret_cast<u16x4*>(hi + i) = h;
    *reinterpret_cast<u16x4*>(lo + i) = l;
  }
}

// ---------------- transpose + split: out[c][r] = in[r][c], 2048x2048 ----
__global__ void k_transpose_split(const float* __restrict__ in,
                                  unsigned short* __restrict__ outh,
                                  unsigned short* __restrict__ outl) {
  __shared__ float tile[32][33];
  int tx = threadIdx.x, ty = threadIdx.y;           // block (32,8)
  int c0 = blockIdx.x * 32, r0 = blockIdx.y * 32;
  #pragma unroll
  for (int j = 0; j < 4; ++j)
    tile[ty + j * 8][tx] = in[(size_t)(r0 + ty + j * 8) * 2048 + c0 + tx];
  __syncthreads();
  #pragma unroll
  for (int j = 0; j < 4; ++j) {
    bfpair p = split2(tile[tx][ty + j * 8]);
    size_t o = (size_t)(c0 + ty + j * 8) * 2048 + r0 + tx;
    outh[o] = p.h; outl[o] = p.l;
  }
}

// ---- GEMM: C[4096][2048] = A[4096][2048] * BT[2048][2048]^T, split operands --
// 128x128 tile, BK=64, 4 waves, 3-pass split MFMA. OUTF32: 1 -> fp32 C (d_out),
// 0 -> split bf16 planes Ch/Cl.
template <int OUTF32>
__global__ __launch_bounds__(256) void k_gemm_sp(const unsigned short* __restrict__ Ah,
                                                 const unsigned short* __restrict__ Al,
                                                 const unsigned short* __restrict__ Bh,
                                                 const unsigned short* __restrict__ Bl,
                                                 void* __restrict__ Ch,
                                                 unsigned short* __restrict__ Cl) {
  __shared__ __align__(16) unsigned short Ash[128 * 64];
  __shared__ __align__(16) unsigned short Asl[128 * 64];
  __shared__ __align__(16) unsigned short Bsh[128 * 64];
  __shared__ __align__(16) unsigned short Bsl[128 * 64];
  const int tid = threadIdx.x;
  const int lane = tid & 63, w = tid >> 6;
  const int lr = lane & 15, lg = lane >> 4;
  const int bm = blockIdx.y, bn = blockIdx.x;
  const int wr = (w >> 1) * 64, wc = (w & 1) * 64;

  f32x4 acc[4][4];
  #pragma unroll
  for (int i = 0; i < 4; ++i)
    #pragma unroll
    for (int j = 0; j < 4; ++j) { f32x4 z = {0.f, 0.f, 0.f, 0.f}; acc[i][j] = z; }

  const size_t aOff = (size_t)(bm * 128) * 2048;
  const size_t bOff = (size_t)(bn * 128) * 2048;

  for (int kt = 0; kt < 32; ++kt) {
    __syncthreads();
    #pragma unroll
    for (int it = 0; it < 4; ++it) {               // stage 128x64 tiles, both planes
      int idx = tid + it * 256;
      int row = idx >> 3, c8 = idx & 7;
      size_t g = (size_t)row * 2048 + kt * 64 + c8 * 8;
      int ld = row * 128 + ((c8 * 16) ^ swzx(row));
      *reinterpret_cast<u16x8*>((char*)Ash + ld) = *reinterpret_cast<const u16x8*>(Ah + aOff + g);
      *reinterpret_cast<u16x8*>((char*)Asl + ld) = *reinterpret_cast<const u16x8*>(Al + aOff + g);
      *reinterpret_cast<u16x8*>((char*)Bsh + ld) = *reinterpret_cast<const u16x8*>(Bh + bOff + g);
      *reinterpret_cast<u16x8*>((char*)Bsl + ld) = *reinterpret_cast<const u16x8*>(Bl + bOff + g);
    }
    __syncthreads();
    #pragma unroll
    for (int ks = 0; ks < 2; ++ks) {
      bf16x8 afh[4], afl[4], bfh[4], bfl[4];
      #pragma unroll
      for (int f = 0; f < 4; ++f) {
        int ar = wr + f * 16 + lr;
        int ao = ar * 128 + ((ks * 64 + lg * 16) ^ swzx(ar));
        afh[f] = *reinterpret_cast<const bf16x8*>((const char*)Ash + ao);
        afl[f] = *reinterpret_cast<const bf16x8*>((const char*)Asl + ao);
        int br = wc + f * 16 + lr;
        int bo = br * 128 + ((ks * 64 + lg * 16) ^ swzx(br));
        bfh[f] = *reinterpret_cast<const bf16x8*>((const char*)Bsh + bo);
        bfl[f] = *reinterpret_cast<const bf16x8*>((const char*)Bsl + bo);
      }
      #pragma unroll
      for (int i = 0; i < 4; ++i)
        #pragma unroll
        for (int j = 0; j < 4; ++j) {
          acc[i][j] = __builtin_amdgcn_mfma_f32_16x16x32_bf16(afl[i], bfh[j], acc[i][j], 0, 0, 0);
          acc[i][j] = __builtin_amdgcn_mfma_f32_16x16x32_bf16(afh[i], bfl[j], acc[i][j], 0, 0, 0);
          acc[i][j] = __builtin_amdgcn_mfma_f32_16x16x32_bf16(afh[i], bfh[j], acc[i][j], 0, 0, 0);
        }
    }
  }

  #pragma unroll
  for (int fm = 0; fm < 4; ++fm)
    #pragma unroll
    for (int fn = 0; fn < 4; ++fn)
      #pragma unroll
      for (int r = 0; r < 4; ++r) {
        int grow = bm * 128 + wr + fm * 16 + lg * 4 + r;   // D row = (lane>>4)*4+r
        int gcol = bn * 128 + wc + fn * 16 + lr;           // D col = lane&15
        float v = acc[fm][fn][r];
        size_t o = (size_t)grow * 2048 + gcol;
        if (OUTF32) ((float*)Ch)[o] = v;
        else { bfpair pp = split2(v); ((unsigned short*)Ch)[o] = pp.h; Cl[o] = pp.l; }
      }
}

// ---------------- fused masked attention + RMSNorm, split operands ----------
// grid.x = b*H+h (32), grid.y = q-tile (16). 8 waves; wave w owns q-rows
// w*16..w*16+15. Q hi/lo in registers; K,V^T,P hi/lo staged in swizzled LDS.
__global__ __launch_bounds__(512) void k_attn_sp(const unsigned short* __restrict__ qh,
                                                 const unsigned short* __restrict__ ql,
                                                 const unsigned short* __restrict__ kh,
                                                 const unsigned short* __restrict__ kl,
                                                 const unsigned short* __restrict__ vh,
                                                 const unsigned short* __restrict__ vl,
                                                 const float* __restrict__ nm,
                                                 const float* __restrict__ rms_scale,
                                                 unsigned short* __restrict__ yh,
                                                 unsigned short* __restrict__ yl) {
  __shared__ __align__(16) unsigned short Ksh[64 * 128];   // [m][k]
  __shared__ __align__(16) unsigned short Ksl[64 * 128];
  __shared__ __align__(16) unsigned short Vth[128 * 64];   // [v][m]
  __shared__ __align__(16) unsigned short Vtl[128 * 64];
  __shared__ __align__(16) unsigned short Psh[128 * 64];   // [n][m]
  __shared__ __align__(16) unsigned short Psl[128 * 64];
  const int tid = threadIdx.x;
  const int lane = tid & 63, w = tid >> 6;
  const int lr = lane & 15, lg = lane >> 4;
  const int bh = blockIdx.x, b = bh >> 4, h = bh & 15;
  const int qt = blockIdx.y;
  const size_t base = (size_t)b * 2048 * 2048 + (size_t)h * 128;  // (b,n,h,*) layout

  bf16x8 aqh[4], aql[4];
  {
    size_t qrow = base + (size_t)(qt * 128 + w * 16 + lr) * 2048;
    #pragma unroll
    for (int ks = 0; ks < 4; ++ks) {
      aqh[ks] = *reinterpret_cast<const bf16x8*>(qh + qrow + ks * 32 + lg * 8);
      aql[ks] = *reinterpret_cast<const bf16x8*>(ql + qrow + ks * 32 + lg * 8);
    }
  }

  f32x4 accY[8];
  #pragma unroll
  for (int i = 0; i < 8; ++i) { f32x4 z = {0.f, 0.f, 0.f, 0.f}; accY[i] = z; }

  const int nT = 2 * qt + 2;
  for (int t = 0; t < nT; ++t) {
    __syncthreads();
    #pragma unroll
    for (int it = 0; it < 2; ++it) {              // stage K tile 64x128, both planes
      int idx = tid + it * 512;
      int row = idx >> 4, c8 = idx & 15;
      size_t g = base + (size_t)(t * 64 + row) * 2048 + c8 * 8;
      int ld = row * 256 + ((c8 * 16) ^ swzx(row));
      *reinterpret_cast<u16x8*>((char*)Ksh + ld) = *reinterpret_cast<const u16x8*>(kh + g);
      *reinterpret_cast<u16x8*>((char*)Ksl + ld) = *reinterpret_cast<const u16x8*>(kl + g);
    }
    #pragma unroll
    for (int it = 0; it < 2; ++it) {              // stage V transposed, both planes
      int idx = tid + it * 512;
      int mrow = idx >> 4, v8 = (idx & 15) * 8;
      size_t g = base + (size_t)(t * 64 + mrow) * 2048 + v8;
      u16x8 vvh = *reinterpret_cast<const u16x8*>(vh + g);
      u16x8 vvl = *reinterpret_cast<const u16x8*>(vl + g);
      #pragma unroll
      for (int j = 0; j < 8; ++j) {
        int vr = v8 + j;
        int ld = vr * 128 + ((mrow * 2) ^ swzx(vr));
        *reinterpret_cast<unsigned short*>((char*)Vth + ld) = (unsigned short)vvh[j];
        *reinterpret_cast<unsigned short*>((char*)Vtl + ld) = (unsigned short)vvl[j];
      }
    }
    __syncthreads();

    // S strip (16 x 64) = Q . K^T  (3-pass split)
    f32x4 accS[4];
    #pragma unroll
    for (int i = 0; i < 4; ++i) { f32x4 z = {0.f, 0.f, 0.f, 0.f}; accS[i] = z; }
    #pragma unroll
    for (int ks = 0; ks < 4; ++ks) {
      #pragma unroll
      for (int fm = 0; fm < 4; ++fm) {
        int br = fm * 16 + lr;
        int bo = br * 256 + ((ks * 64 + lg * 16) ^ swzx(br));
        bf16x8 bkh = *reinterpret_cast<const bf16x8*>((const char*)Ksh + bo);
        bf16x8 bkl = *reinterpret_cast<const bf16x8*>((const char*)Ksl + bo);
        accS[fm] = __builtin_amdgcn_mfma_f32_16x16x32_bf16(aql[ks], bkh, accS[fm], 0, 0, 0);
        accS[fm] = __builtin_amdgcn_mfma_f32_16x16x32_bf16(aqh[ks], bkl, accS[fm], 0, 0, 0);
        accS[fm] = __builtin_amdgcn_mfma_f32_16x16x32_bf16(aqh[ks], bkh, accS[fm], 0, 0, 0);
      }
    }

    // mask-multiply fp32, split to bf16 hi/lo, park P strip (wave-private rows)
    #pragma unroll
    for (int fm = 0; fm < 4; ++fm)
      #pragma unroll
      for (int r = 0; r < 4; ++r) {
        int nrow = qt * 128 + w * 16 + lg * 4 + r;
        int mcol = t * 64 + fm * 16 + lr;
        float pv = accS[fm][r] * nm[(size_t)nrow * 2048 + mcol];
        bfpair pp = split2(pv);
        int pr = w * 16 + lg * 4 + r, pc = fm * 16 + lr;
        int ld = pr * 128 + ((pc * 2) ^ swzx(pr));
        *reinterpret_cast<unsigned short*>((char*)Psh + ld) = pp.h;
        *reinterpret_cast<unsigned short*>((char*)Psl + ld) = pp.l;
      }

    // Y strip (16 x 128) += P (16 x 64) . V (64 x 128)  (3-pass split)
    #pragma unroll
    for (int ks = 0; ks < 2; ++ks) {
      int ar = w * 16 + lr;
      int ao = ar * 128 + ((ks * 64 + lg * 16) ^ swzx(ar));
      bf16x8 aph = *reinterpret_cast<const bf16x8*>((const char*)Psh + ao);
      bf16x8 apl = *reinterpret_cast<const bf16x8*>((const char*)Psl + ao);
      #pragma unroll
      for (int fv = 0; fv < 8; ++fv) {
        int br = fv * 16 + lr;
        int bo = br * 128 + ((ks * 64 + lg * 16) ^ swzx(br));
        bf16x8 bvh = *reinterpret_cast<const bf16x8*>((const char*)Vth + bo);
        bf16x8 bvl = *reinterpret_cast<const bf16x8*>((const char*)Vtl + bo);
        accY[fv] = __builtin_amdgcn_mfma_f32_16x16x32_bf16(apl, bvh, accY[fv], 0, 0, 0);
        accY[fv] = __builtin_amdgcn_mfma_f32_16x16x32_bf16(aph, bvl, accY[fv], 0, 0, 0);
        accY[fv] = __builtin_amdgcn_mfma_f32_16x16x32_bf16(aph, bvh, accY[fv], 0, 0, 0);
      }
    }
  }

  // epilogue: RMSNorm over V=128 per row, write y hi/lo planes (b,n,h,v)
  #pragma unroll
  for (int r = 0; r < 4; ++r) {
    float sq = 0.f;
    #pragma unroll
    for (int fv = 0; fv < 8; ++fv) { float y = accY[fv][r]; sq += y * y; }
    sq += __shfl_xor(sq, 1); sq += __shfl_xor(sq, 2);
    sq += __shfl_xor(sq, 4); sq += __shfl_xor(sq, 8);
    float scale = rsqrtf(sq * (1.0f / 128.0f) + 1e-6f);
    int nrow = qt * 128 + w * 16 + lg * 4 + r;
    size_t orow = ((size_t)b * 2048 + nrow) * 2048 + (size_t)h * 128;
    #pragma unroll
    for (int fv = 0; fv < 8; ++fv) {
      int col = fv * 16 + lr;
      float yv = accY[fv][r] * scale * rms_scale[col];
      bfpair pp = split2(yv);
      yh[orow + col] = pp.h; yl[orow + col] = pp.l;
    }
  }
}

extern "C" void kernel_launch(void* const* d_in, const int* in_sizes, int n_in,
                              void* d_out, int out_size, void* d_ws, size_t ws_size,
                              hipStream_t stream) {
  (void)in_sizes; (void)n_in; (void)out_size; (void)ws_size;
  const float* x  = (const float*)d_in[0];
  const float* nm = (const float*)d_in[1];
  const float* wq = (const float*)d_in[2];
  const float* wk = (const float*)d_in[3];
  const float* wv = (const float*)d_in[4];
  const float* rs = (const float*)d_in[5];
  const float* wo = (const float*)d_in[6];

  unsigned short* p = (unsigned short*)d_ws;     // 151 MB total (bf16 planes)
  unsigned short* xh  = p; p += 8388608;         // x hi; reused as y hi after attn
  unsigned short* xl  = p; p += 8388608;         // x lo; reused as y lo
  unsigned short* wth = p; p += 4194304;         // transposed weight hi (reused x4)
  unsigned short* wtl = p; p += 4194304;
  unsigned short* qhp = p; p += 8388608;
  unsigned short* qlp = p; p += 8388608;
  unsigned short* khp = p; p += 8388608;
  unsigned short* klp = p; p += 8388608;
  unsigned short* vhp = p; p += 8388608;
  unsigned short* vlp = p; p += 8388608;

  k_split<<<dim3(2048), dim3(256), 0, stream>>>(x, xh, xl, 8388608);

  k_transpose_split<<<dim3(64, 64), dim3(32, 8), 0, stream>>>(wq, wth, wtl);
  k_gemm_sp<0><<<dim3(16, 32), dim3(256), 0, stream>>>(xh, xl, wth, wtl, qhp, qlp);
  k_transpose_split<<<dim3(64, 64), dim3(32, 8), 0, stream>>>(wk, wth, wtl);
  k_gemm_sp<0><<<dim3(16, 32), dim3(256), 0, stream>>>(xh, xl, wth, wtl, khp, klp);
  k_transpose_split<<<dim3(64, 64), dim3(32, 8), 0, stream>>>(wv, wth, wtl);
  k_gemm_sp<0><<<dim3(16, 32), dim3(256), 0, stream>>>(xh, xl, wth, wtl, vhp, vlp);
  k_transpose_split<<<dim3(64, 64), dim3(32, 8), 0, stream>>>(wo, wth, wtl);

  // y written into the (now dead) x planes
  k_attn_sp<<<dim3(32, 16), dim3(512), 0, stream>>>(qhp, qlp, khp, klp, vhp, vlp,
                                                    nm, rs, xh, xl);

  k_gemm_sp<1><<<dim3(16, 32), dim3(256), 0, stream>>>(xh, xl, wth, wtl, d_out, nullptr);
}

// Round 5
// 587.226 us; speedup vs baseline: 1.4309x; 1.4309x over previous
//
#include <hip/hip_runtime.h>
#include <hip/hip_bf16.h>

// TransNormer: causal linear attention, B=2 N=2048 D=2048 H=16 I=1 K=V=128.
// Split-bf16 (hi/lo) 3-pass MFMA everywhere => fp32-fidelity (absmax 0.0156).
// R4: attn = paired q-tiles (uniform work) + reg-prefetch pipeline with raw
// barriers (no vmcnt drain); GEMM = global_load_lds width-16 staging.

typedef short          bf16x8 __attribute__((ext_vector_type(8)));
typedef unsigned short u16x8  __attribute__((ext_vector_type(8)));
typedef unsigned short u16x4  __attribute__((ext_vector_type(4)));
typedef float          f32x4  __attribute__((ext_vector_type(4)));

#define DEV static __device__ __forceinline__

DEV unsigned short f2bf(float f) {  // RNE fp32 -> bf16 bits
  union { float f; unsigned u; } v; v.f = f;
  unsigned r = v.u + 0x7fffu + ((v.u >> 16) & 1u);
  return (unsigned short)(r >> 16);
}
DEV float bf2f(unsigned short h) {
  union { unsigned u; float f; } v; v.u = ((unsigned)h) << 16; return v.f;
}
struct bfpair { unsigned short h, l; };
DEV bfpair split2(float x) {
  bfpair p; p.h = f2bf(x); p.l = f2bf(x - bf2f(p.h)); return p;
}

// XOR swizzle of byte bits 4-6 (bank-group spread)
DEV int swzx(int row) { return (((row & 7) ^ ((row >> 3) & 7)) << 4); }

typedef const unsigned int __attribute__((address_space(1)))* gas_t;
typedef unsigned int __attribute__((address_space(3)))* las_t;
DEV void gld16(const unsigned short* g, void* l) {   // global -> LDS DMA, 16B/lane
  __builtin_amdgcn_global_load_lds((gas_t)(const void*)g, (las_t)l, 16, 0, 0);
}

// ---------------- cast fp32 -> bf16 hi/lo planes ----------------
__global__ void k_split(const float* __restrict__ in, unsigned short* __restrict__ hi,
                        unsigned short* __restrict__ lo, int n) {
  int i = (blockIdx.x * blockDim.x + threadIdx.x) * 4;
  int stride = gridDim.x * blockDim.x * 4;
  for (; i < n; i += stride) {
    float4 v = *reinterpret_cast<const float4*>(in + i);
    bfpair a = split2(v.x), b = split2(v.y), c = split2(v.z), d = split2(v.w);
    u16x4 h, l;
    h[0] = a.h; h[1] = b.h; h[2] = c.h; h[3] = d.h;
    l[0] = a.l; l[1] = b.l; l[2] = c.l; l[3] = d.l;
    *reinterpret_cast<u16x4*>(hi + i) = h;
    *reinterpret_cast<u16x4*>(lo + i) = l;
  }
}

// ---------------- transpose + split: out[c][r] = in[r][c], 2048x2048 ----
__global__ void k_transpose_split(const float* __restrict__ in,
                                  unsigned short* __restrict__ outh,
                                  unsigned short* __restrict__ outl) {
  __shared__ float tile[32][33];
  int tx = threadIdx.x, ty = threadIdx.y;           // block (32,8)
  int c0 = blockIdx.x * 32, r0 = blockIdx.y * 32;
  #pragma unroll
  for (int j = 0; j < 4; ++j)
    tile[ty + j * 8][tx] = in[(size_t)(r0 + ty + j * 8) * 2048 + c0 + tx];
  __syncthreads();
  #pragma unroll
  for (int j = 0; j < 4; ++j) {
    bfpair p = split2(tile[tx][ty + j * 8]);
    size_t o = (size_t)(c0 + ty + j * 8) * 2048 + r0 + tx;
    outh[o] = p.h; outl[o] = p.l;
  }
}

// ---- GEMM: C[4096][2048] = A[4096][2048] * BT[2048][2048]^T, split operands --
// 128x128 tile, BK=64, 4 waves, 3-pass split MFMA, global_load_lds staging.
// LDS slot (row,c) holds global (row, c^swz(row)) -- read formula unchanged.
template <int OUTF32>
__global__ __launch_bounds__(256) void k_gemm_sp(const unsigned short* __restrict__ Ah,
                                                 const unsigned short* __restrict__ Al,
                                                 const unsigned short* __restrict__ Bh,
                                                 const unsigned short* __restrict__ Bl,
                                                 void* __restrict__ Ch,
                                                 unsigned short* __restrict__ Cl) {
  __shared__ __align__(16) unsigned short Ash[128 * 64];
  __shared__ __align__(16) unsigned short Asl[128 * 64];
  __shared__ __align__(16) unsigned short Bsh[128 * 64];
  __shared__ __align__(16) unsigned short Bsl[128 * 64];
  const int tid = threadIdx.x;
  const int lane = tid & 63, w = tid >> 6;
  const int lr = lane & 15, lg = lane >> 4;
  const int bm = blockIdx.y, bn = blockIdx.x;
  const int wr = (w >> 1) * 64, wc = (w & 1) * 64;

  f32x4 acc[4][4];
  #pragma unroll
  for (int i = 0; i < 4; ++i)
    #pragma unroll
    for (int j = 0; j < 4; ++j) { f32x4 z = {0.f, 0.f, 0.f, 0.f}; acc[i][j] = z; }

  const size_t aOff = (size_t)(bm * 128) * 2048;
  const size_t bOff = (size_t)(bn * 128) * 2048;

  for (int kt = 0; kt < 32; ++kt) {
    __syncthreads();                               // prev reads done; DMA may begin
    #pragma unroll
    for (int it = 0; it < 4; ++it) {               // 16B/lane DMA, lane-linear dest
      int row = it * 32 + (tid >> 3);
      int cb  = ((tid & 7) * 16) ^ swzx(row);      // pre-swizzled source col (bytes)
      size_t g = (size_t)row * 2048 + kt * 64 + (cb >> 1);
      int ld = it * 4096 + tid * 16;               // = row*128 + (tid&7)*16
      gld16(Ah + aOff + g, (char*)Ash + ld);
      gld16(Al + aOff + g, (char*)Asl + ld);
      gld16(Bh + bOff + g, (char*)Bsh + ld);
      gld16(Bl + bOff + g, (char*)Bsl + ld);
    }
    __syncthreads();                               // drains vmcnt(0): DMA landed
    #pragma unroll
    for (int ks = 0; ks < 2; ++ks) {
      bf16x8 afh[4], afl[4], bfh[4], bfl[4];
      #pragma unroll
      for (int f = 0; f < 4; ++f) {
        int ar = wr + f * 16 + lr;
        int ao = ar * 128 + ((ks * 64 + lg * 16) ^ swzx(ar));
        afh[f] = *reinterpret_cast<const bf16x8*>((const char*)Ash + ao);
        afl[f] = *reinterpret_cast<const bf16x8*>((const char*)Asl + ao);
        int br = wc + f * 16 + lr;
        int bo = br * 128 + ((ks * 64 + lg * 16) ^ swzx(br));
        bfh[f] = *reinterpret_cast<const bf16x8*>((const char*)Bsh + bo);
        bfl[f] = *reinterpret_cast<const bf16x8*>((const char*)Bsl + bo);
      }
      #pragma unroll
      for (int i = 0; i < 4; ++i)
        #pragma unroll
        for (int j = 0; j < 4; ++j) {
          acc[i][j] = __builtin_amdgcn_mfma_f32_16x16x32_bf16(afl[i], bfh[j], acc[i][j], 0, 0, 0);
          acc[i][j] = __builtin_amdgcn_mfma_f32_16x16x32_bf16(afh[i], bfl[j], acc[i][j], 0, 0, 0);
          acc[i][j] = __builtin_amdgcn_mfma_f32_16x16x32_bf16(afh[i], bfh[j], acc[i][j], 0, 0, 0);
        }
    }
  }

  #pragma unroll
  for (int fm = 0; fm < 4; ++fm)
    #pragma unroll
    for (int fn = 0; fn < 4; ++fn)
      #pragma unroll
      for (int r = 0; r < 4; ++r) {
        int grow = bm * 128 + wr + fm * 16 + lg * 4 + r;   // D row = (lane>>4)*4+r
        int gcol = bn * 128 + wc + fn * 16 + lr;           // D col = lane&15
        float v = acc[fm][fn][r];
        size_t o = (size_t)grow * 2048 + gcol;
        if (OUTF32) ((float*)Ch)[o] = v;
        else { bfpair pp = split2(v); ((unsigned short*)Ch)[o] = pp.h; Cl[o] = pp.l; }
      }
}

// ---------------- fused masked attention + RMSNorm, split operands ----------
// grid (32, 8): block handles q-tiles {y, 15-y} => uniform 34 KV-tiles.
// Reg-prefetch pipeline: K/V for tile t+1 and mask for tile t are loaded into
// registers during tile t's compute; raw s_barrier (lgkm-only waits) keeps
// the vmem prefetch in flight across barriers.
__global__ __launch_bounds__(512) void k_attn_sp(const unsigned short* __restrict__ qh,
                                                 const unsigned short* __restrict__ ql,
                                                 const unsigned short* __restrict__ kh,
                                                 const unsigned short* __restrict__ kl,
                                                 const unsigned short* __restrict__ vh,
                                                 const unsigned short* __restrict__ vl,
                                                 const float* __restrict__ nm,
                                                 const float* __restrict__ rms_scale,
                                                 unsigned short* __restrict__ yh,
                                                 unsigned short* __restrict__ yl) {
  __shared__ __align__(16) unsigned short Ksh[64 * 128];   // [m][k]
  __shared__ __align__(16) unsigned short Ksl[64 * 128];
  __shared__ __align__(16) unsigned short Vth[128 * 64];   // [v][m]
  __shared__ __align__(16) unsigned short Vtl[128 * 64];
  __shared__ __align__(16) unsigned short Psh[128 * 64];   // [n][m] (wave-private rows)
  __shared__ __align__(16) unsigned short Psl[128 * 64];
  const int tid = threadIdx.x;
  const int lane = tid & 63, w = tid >> 6;
  const int lr = lane & 15, lg = lane >> 4;
  const int bh = blockIdx.x, b = bh >> 4, h = bh & 15;
  const size_t base = (size_t)b * 2048 * 2048 + (size_t)h * 128;  // (b,n,h,*) layout

  const int prow = tid >> 4;                 // staging row 0..31 (+32 for it=1)
  const int pc8  = tid & 15;                 // 16B chunk 0..15

  #pragma unroll
  for (int pi = 0; pi < 2; ++pi) {
    const int qt = pi ? (15 - (int)blockIdx.y) : (int)blockIdx.y;
    const int nT = 2 * qt + 2;

    // Q fragments (hi/lo) in registers
    bf16x8 aqh[4], aql[4];
    {
      size_t qrow = base + (size_t)(qt * 128 + w * 16 + lr) * 2048;
      #pragma unroll
      for (int ks = 0; ks < 4; ++ks) {
        aqh[ks] = *reinterpret_cast<const bf16x8*>(qh + qrow + ks * 32 + lg * 8);
        aql[ks] = *reinterpret_cast<const bf16x8*>(ql + qrow + ks * 32 + lg * 8);
      }
    }

    f32x4 accY[8];
    #pragma unroll
    for (int i = 0; i < 8; ++i) { f32x4 z = {0.f, 0.f, 0.f, 0.f}; accY[i] = z; }

    // prologue: prefetch tile 0 K/V into registers
    u16x8 krh[2], krl[2], vrh[2], vrl[2];
    #pragma unroll
    for (int it = 0; it < 2; ++it) {
      size_t g = base + (size_t)(it * 32 + prow) * 2048 + pc8 * 8;
      krh[it] = *reinterpret_cast<const u16x8*>(kh + g);
      krl[it] = *reinterpret_cast<const u16x8*>(kl + g);
      vrh[it] = *reinterpret_cast<const u16x8*>(vh + g);
      vrl[it] = *reinterpret_cast<const u16x8*>(vl + g);
    }

    for (int t = 0; t < nT; ++t) {
      // ---- barrier 1: everyone done READING previous tile's K/V LDS ----
      asm volatile("s_waitcnt lgkmcnt(0)" ::: "memory");
      __builtin_amdgcn_s_barrier();

      // ---- stage K (vector) + V (transpose scatter) from prefetch regs ----
      #pragma unroll
      for (int it = 0; it < 2; ++it) {
        int row = it * 32 + prow;
        int ldk = row * 256 + ((pc8 * 16) ^ swzx(row));
        *reinterpret_cast<u16x8*>((char*)Ksh + ldk) = krh[it];
        *reinterpret_cast<u16x8*>((char*)Ksl + ldk) = krl[it];
        int v8 = pc8 * 8;
        #pragma unroll
        for (int j = 0; j < 8; ++j) {
          int vr = v8 + j;
          int ldv = vr * 128 + ((row * 2) ^ swzx(vr));
          *reinterpret_cast<unsigned short*>((char*)Vth + ldv) = (unsigned short)vrh[it][j];
          *reinterpret_cast<unsigned short*>((char*)Vtl + ldv) = (unsigned short)vrl[it][j];
        }
      }

      // ---- issue mask loads for tile t (consumed after QK^T) ----
      float nmv[4][4];
      #pragma unroll
      for (int fm = 0; fm < 4; ++fm)
        #pragma unroll
        for (int r = 0; r < 4; ++r)
          nmv[fm][r] = nm[(size_t)(qt * 128 + w * 16 + lg * 4 + r) * 2048 +
                          t * 64 + fm * 16 + lr];

      // ---- issue K/V prefetch for tile t+1 (lands next iteration) ----
      if (t + 1 < nT) {
        #pragma unroll
        for (int it = 0; it < 2; ++it) {
          size_t g = base + (size_t)((t + 1) * 64 + it * 32 + prow) * 2048 + pc8 * 8;
          krh[it] = *reinterpret_cast<const u16x8*>(kh + g);
          krl[it] = *reinterpret_cast<const u16x8*>(kl + g);
          vrh[it] = *reinterpret_cast<const u16x8*>(vh + g);
          vrl[it] = *reinterpret_cast<const u16x8*>(vl + g);
        }
      }

      // ---- barrier 2: K/V LDS writes visible to all waves ----
      asm volatile("s_waitcnt lgkmcnt(0)" ::: "memory");
      __builtin_amdgcn_s_barrier();

      // ---- S strip (16 x 64) = Q . K^T  (3-pass split) ----
      f32x4 accS[4];
      #pragma unroll
      for (int i = 0; i < 4; ++i) { f32x4 z = {0.f, 0.f, 0.f, 0.f}; accS[i] = z; }
      #pragma unroll
      for (int ks = 0; ks < 4; ++ks) {
        #pragma unroll
        for (int fm = 0; fm < 4; ++fm) {
          int br = fm * 16 + lr;
          int bo = br * 256 + ((ks * 64 + lg * 16) ^ swzx(br));
          bf16x8 bkh = *reinterpret_cast<const bf16x8*>((const char*)Ksh + bo);
          bf16x8 bkl = *reinterpret_cast<const bf16x8*>((const char*)Ksl + bo);
          accS[fm] = __builtin_amdgcn_mfma_f32_16x16x32_bf16(aql[ks], bkh, accS[fm], 0, 0, 0);
          accS[fm] = __builtin_amdgcn_mfma_f32_16x16x32_bf16(aqh[ks], bkl, accS[fm], 0, 0, 0);
          accS[fm] = __builtin_amdgcn_mfma_f32_16x16x32_bf16(aqh[ks], bkh, accS[fm], 0, 0, 0);
        }
      }

      // ---- mask-multiply fp32, split, park P strip (wave-private rows) ----
      #pragma unroll
      for (int fm = 0; fm < 4; ++fm)
        #pragma unroll
        for (int r = 0; r < 4; ++r) {
          float pv = accS[fm][r] * nmv[fm][r];
          bfpair pp = split2(pv);
          int pr = w * 16 + lg * 4 + r, pc = fm * 16 + lr;
          int ld = pr * 128 + ((pc * 2) ^ swzx(pr));
          *reinterpret_cast<unsigned short*>((char*)Psh + ld) = pp.h;
          *reinterpret_cast<unsigned short*>((char*)Psl + ld) = pp.l;
        }

      // ---- Y strip (16 x 128) += P . V  (3-pass split) ----
      #pragma unroll
      for (int ks = 0; ks < 2; ++ks) {
        int ar = w * 16 + lr;
        int ao = ar * 128 + ((ks * 64 + lg * 16) ^ swzx(ar));
        bf16x8 aph = *reinterpret_cast<const bf16x8*>((const char*)Psh + ao);
        bf16x8 apl = *reinterpret_cast<const bf16x8*>((const char*)Psl + ao);
        #pragma unroll
        for (int fv = 0; fv < 8; ++fv) {
          int br = fv * 16 + lr;
          int bo = br * 128 + ((ks * 64 + lg * 16) ^ swzx(br));
          bf16x8 bvh = *reinterpret_cast<const bf16x8*>((const char*)Vth + bo);
          bf16x8 bvl = *reinterpret_cast<const bf16x8*>((const char*)Vtl + bo);
          accY[fv] = __builtin_amdgcn_mfma_f32_16x16x32_bf16(apl, bvh, accY[fv], 0, 0, 0);
          accY[fv] = __builtin_amdgcn_mfma_f32_16x16x32_bf16(aph, bvl, accY[fv], 0, 0, 0);
          accY[fv] = __builtin_amdgcn_mfma_f32_16x16x32_bf16(aph, bvh, accY[fv], 0, 0, 0);
        }
      }
    }

    // epilogue: RMSNorm over V=128 per row, write y hi/lo planes (b,n,h,v)
    #pragma unroll
    for (int r = 0; r < 4; ++r) {
      float sq = 0.f;
      #pragma unroll
      for (int fv = 0; fv < 8; ++fv) { float y = accY[fv][r]; sq += y * y; }
      sq += __shfl_xor(sq, 1); sq += __shfl_xor(sq, 2);
      sq += __shfl_xor(sq, 4); sq += __shfl_xor(sq, 8);
      float scale = rsqrtf(sq * (1.0f / 128.0f) + 1e-6f);
      int nrow = qt * 128 + w * 16 + lg * 4 + r;
      size_t orow = ((size_t)b * 2048 + nrow) * 2048 + (size_t)h * 128;
      #pragma unroll
      for (int fv = 0; fv < 8; ++fv) {
        int col = fv * 16 + lr;
        float yv = accY[fv][r] * scale * rms_scale[col];
        bfpair pp = split2(yv);
        yh[orow + col] = pp.h; yl[orow + col] = pp.l;
      }
    }
  }
}

extern "C" void kernel_launch(void* const* d_in, const int* in_sizes, int n_in,
                              void* d_out, int out_size, void* d_ws, size_t ws_size,
                              hipStream_t stream) {
  (void)in_sizes; (void)n_in; (void)out_size; (void)ws_size;
  const float* x  = (const float*)d_in[0];
  const float* nm = (const float*)d_in[1];
  const float* wq = (const float*)d_in[2];
  const float* wk = (const float*)d_in[3];
  const float* wv = (const float*)d_in[4];
  const float* rs = (const float*)d_in[5];
  const float* wo = (const float*)d_in[6];

  unsigned short* p = (unsigned short*)d_ws;     // 151 MB total (bf16 planes)
  unsigned short* xh  = p; p += 8388608;         // x hi; reused as y hi after attn
  unsigned short* xl  = p; p += 8388608;         // x lo; reused as y lo
  unsigned short* wth = p; p += 4194304;         // transposed weight hi (reused x4)
  unsigned short* wtl = p; p += 4194304;
  unsigned short* qhp = p; p += 8388608;
  unsigned short* qlp = p; p += 8388608;
  unsigned short* khp = p; p += 8388608;
  unsigned short* klp = p; p += 8388608;
  unsigned short* vhp = p; p += 8388608;
  unsigned short* vlp = p; p += 8388608;

  k_split<<<dim3(2048), dim3(256), 0, stream>>>(x, xh, xl, 8388608);

  k_transpose_split<<<dim3(64, 64), dim3(32, 8), 0, stream>>>(wq, wth, wtl);
  k_gemm_sp<0><<<dim3(16, 32), dim3(256), 0, stream>>>(xh, xl, wth, wtl, qhp, qlp);
  k_transpose_split<<<dim3(64, 64), dim3(32, 8), 0, stream>>>(wk, wth, wtl);
  k_gemm_sp<0><<<dim3(16, 32), dim3(256), 0, stream>>>(xh, xl, wth, wtl, khp, klp);
  k_transpose_split<<<dim3(64, 64), dim3(32, 8), 0, stream>>>(wv, wth, wtl);
  k_gemm_sp<0><<<dim3(16, 32), dim3(256), 0, stream>>>(xh, xl, wth, wtl, vhp, vlp);
  k_transpose_split<<<dim3(64, 64), dim3(32, 8), 0, stream>>>(wo, wth, wtl);

  // y written into the (now dead) x planes; paired q-tiles -> grid (32, 8)
  k_attn_sp<<<dim3(32, 8), dim3(512), 0, stream>>>(qhp, qlp, khp, klp, vhp, vlp,
                                                   nm, rs, xh, xl);

  k_gemm_sp<1><<<dim3(16, 32), dim3(256), 0, stream>>>(xh, xl, wth, wtl, d_out, nullptr);
}

// Round 8
// 298.982 us; speedup vs baseline: 2.8105x; 1.9641x over previous
//
#include <hip/hip_runtime.h>
#include <hip/hip_bf16.h>

// TransNormer: causal linear attention, B=2 N=2048 D=2048 H=16 I=1 K=V=128.
// R8 = R7 with the k_gemm1 LDS staging stride fixed (it*4096, not it*8192:
// 32 rows x 128 B per staging step; the 8192 left As rows 32-63 unwritten ->
// NaN garbage, and spilled writes past the LDS allocation).
// Precision: all tensors single-plane fp16 (~2^-12 rel/tensor), 1-pass
// mfma_f32_16x16x32_f16, fp32 accumulation. Predicted absmax ~0.03-0.05.

typedef _Float16 f16x8 __attribute__((ext_vector_type(8)));
typedef _Float16 f16x4 __attribute__((ext_vector_type(4)));
typedef float    f32x4 __attribute__((ext_vector_type(4)));

#define DEV static __device__ __forceinline__

// XOR swizzle of byte bits 4-6 (bank-group spread); 16B blocks are atomic.
DEV int swzx(int row) { return (((row & 7) ^ ((row >> 3) & 7)) << 4); }

typedef const unsigned int __attribute__((address_space(1)))* gas_t;
typedef unsigned int __attribute__((address_space(3)))* las_t;
DEV void gld16(const void* g, void* l) {   // global -> LDS DMA, 16B/lane
  __builtin_amdgcn_global_load_lds((gas_t)g, (las_t)l, 16, 0, 0);
}

// ---------------- cast fp32 -> fp16, contiguous ----------------
__global__ void k_cast_h(const float* __restrict__ in, _Float16* __restrict__ out, int n) {
  int i = (blockIdx.x * blockDim.x + threadIdx.x) * 4;
  int stride = gridDim.x * blockDim.x * 4;
  for (; i < n; i += stride) {
    float4 v = *reinterpret_cast<const float4*>(in + i);
    f16x4 o;
    o[0] = (_Float16)v.x; o[1] = (_Float16)v.y;
    o[2] = (_Float16)v.z; o[3] = (_Float16)v.w;
    *reinterpret_cast<f16x4*>(out + i) = o;
  }
}

// ------- transpose + cast: out[c][r] = fp16(in[r][c]), 2048x2048 -------
__global__ void k_transpose_h(const float* __restrict__ in, _Float16* __restrict__ out) {
  __shared__ float tile[32][33];
  int tx = threadIdx.x, ty = threadIdx.y;           // block (32,8)
  int c0 = blockIdx.x * 32, r0 = blockIdx.y * 32;
  #pragma unroll
  for (int j = 0; j < 4; ++j)
    tile[ty + j * 8][tx] = in[(size_t)(r0 + ty + j * 8) * 2048 + c0 + tx];
  __syncthreads();
  #pragma unroll
  for (int j = 0; j < 4; ++j)
    out[(size_t)(c0 + ty + j * 8) * 2048 + r0 + tx] = (_Float16)tile[tx][ty + j * 8];
}

// ------- batched transpose: v (b,n,h,v) fp16 -> vT (b*h, v, n) fp16 -------
__global__ void k_transpose_v(const _Float16* __restrict__ in, _Float16* __restrict__ out) {
  __shared__ _Float16 tile[32][33];
  int tx = threadIdx.x, ty = threadIdx.y;           // block (32,8)
  int v0 = blockIdx.x * 32, n0 = blockIdx.y * 32, bh = blockIdx.z;
  int b = bh >> 4, h = bh & 15;
  #pragma unroll
  for (int j = 0; j < 4; ++j)
    tile[ty + j * 8][tx] =
        in[((size_t)(b * 2048 + n0 + ty + j * 8) * 16 + h) * 128 + v0 + tx];
  __syncthreads();
  #pragma unroll
  for (int j = 0; j < 4; ++j)
    out[((size_t)bh * 128 + v0 + ty + j * 8) * 2048 + n0 + tx] = tile[tx][ty + j * 8];
}

// ---- GEMM: C[4096][2048] = A[4096][2048] * B[2048][2048]^T, fp16 1-pass ----
// 128x128 tile, BK=64, 4 waves, global_load_lds staging (pre-swizzled source,
// linear dest), 32KB LDS. OUTF32: 1 -> fp32 C (d_out), 0 -> fp16 C.
template <int OUTF32>
__global__ __launch_bounds__(256) void k_gemm1(const _Float16* __restrict__ A,
                                               const _Float16* __restrict__ B,
                                               void* __restrict__ C) {
  __shared__ __align__(16) _Float16 As[128 * 64];
  __shared__ __align__(16) _Float16 Bs[128 * 64];
  const int tid = threadIdx.x;
  const int lane = tid & 63, w = tid >> 6;
  const int lr = lane & 15, lg = lane >> 4;
  const int bm = blockIdx.y, bn = blockIdx.x;
  const int wr = (w >> 1) * 64, wc = (w & 1) * 64;

  f32x4 acc[4][4];
  #pragma unroll
  for (int i = 0; i < 4; ++i)
    #pragma unroll
    for (int j = 0; j < 4; ++j) { f32x4 z = {0.f, 0.f, 0.f, 0.f}; acc[i][j] = z; }

  const size_t aOff = (size_t)(bm * 128) * 2048;
  const size_t bOff = (size_t)(bn * 128) * 2048;

  for (int kt = 0; kt < 32; ++kt) {
    __syncthreads();                               // prev readers done
    #pragma unroll
    for (int it = 0; it < 4; ++it) {               // 16B/lane DMA, lane-linear dest
      int row = it * 32 + (tid >> 3);
      int cb  = ((tid & 7) * 16) ^ swzx(row);      // pre-swizzled source col (bytes)
      size_t g = (size_t)row * 2048 + kt * 64 + (cb >> 1);
      int ld = it * 4096 + tid * 16;               // bytes: 32 rows x 128 B per it
      gld16(A + aOff + g, (char*)As + ld);
      gld16(B + bOff + g, (char*)Bs + ld);
    }
    __syncthreads();                               // drains vmcnt(0): DMA landed
    #pragma unroll
    for (int ks = 0; ks < 2; ++ks) {
      f16x8 af[4], bf[4];
      #pragma unroll
      for (int f = 0; f < 4; ++f) {
        int ar = wr + f * 16 + lr;
        af[f] = *reinterpret_cast<const f16x8*>((const char*)As + ar * 128 +
                                                ((ks * 64 + lg * 16) ^ swzx(ar)));
        int br = wc + f * 16 + lr;
        bf[f] = *reinterpret_cast<const f16x8*>((const char*)Bs + br * 128 +
                                                ((ks * 64 + lg * 16) ^ swzx(br)));
      }
      #pragma unroll
      for (int i = 0; i < 4; ++i)
        #pragma unroll
        for (int j = 0; j < 4; ++j)
          acc[i][j] = __builtin_amdgcn_mfma_f32_16x16x32_f16(af[i], bf[j], acc[i][j], 0, 0, 0);
    }
  }

  #pragma unroll
  for (int fm = 0; fm < 4; ++fm)
    #pragma unroll
    for (int fn = 0; fn < 4; ++fn)
      #pragma unroll
      for (int r = 0; r < 4; ++r) {
        int grow = bm * 128 + wr + fm * 16 + lg * 4 + r;   // D row = (lane>>4)*4+r
        int gcol = bn * 128 + wc + fn * 16 + lr;           // D col = lane&15
        float v = acc[fm][fn][r];
        size_t o = (size_t)grow * 2048 + gcol;
        if (OUTF32) ((float*)C)[o] = v;
        else        ((_Float16*)C)[o] = (_Float16)v;
      }
}

// ---------------- fused masked attention + RMSNorm, fp16 1-pass ----------
// grid (32, 8): block does q-tiles {y, 15-y} (uniform 34 KV-tiles). 8 waves x
// 16 q-rows. K, V^T DMA-staged into double-buffered LDS; P single fp16 plane
// (wave-private rows). Mask loads issued BEFORE next-tile DMA so the nmv wait
// is vmcnt(8), keeping the prefetch in flight through the tile compute.
__global__ __launch_bounds__(512) void k_attn1(const _Float16* __restrict__ qv,
                                               const _Float16* __restrict__ kv,
                                               const _Float16* __restrict__ vt,
                                               const float* __restrict__ nm,
                                               const float* __restrict__ rms_scale,
                                               _Float16* __restrict__ y) {
  __shared__ __align__(16) _Float16 Ks[2][64 * 128];   // [m][k] 16KB x2
  __shared__ __align__(16) _Float16 Vs[2][128 * 64];   // [v][m] 16KB x2
  __shared__ __align__(16) _Float16 Ps[128 * 64];      // [n][m] 16KB
  const int tid = threadIdx.x;
  const int lane = tid & 63, w = tid >> 6;
  const int lr = lane & 15, lg = lane >> 4;
  const int bh = blockIdx.x, b = bh >> 4, h = bh & 15;
  const size_t base  = (size_t)b * 2048 * 2048 + (size_t)h * 128;  // (b,n,h,*)
  const size_t vbase = (size_t)bh * 128 * 2048;                    // (bh,v,n)

  const int krow = tid >> 4, kc = tid & 15;    // K stage: 32 rows/it, 16 chunks
  const int vrow = tid >> 3, vc = tid & 7;     // V stage: 64 rows/it, 8 chunks

  auto STAGE = [&](int t, int bufi) {
    #pragma unroll
    for (int it = 0; it < 2; ++it) {
      int kr = it * 32 + krow;
      int gk = ((kc * 16) ^ swzx(kr)) >> 1;
      gld16(kv + base + (size_t)(t * 64 + kr) * 2048 + gk,
            (char*)Ks[bufi] + it * 8192 + tid * 16);   // 32 rows x 256 B per it
      int vr = it * 64 + vrow;
      int gv = ((vc * 16) ^ swzx(vr)) >> 1;
      gld16(vt + vbase + (size_t)vr * 2048 + t * 64 + gv,
            (char*)Vs[bufi] + it * 8192 + tid * 16);   // 64 rows x 128 B per it
    }
  };

  #pragma unroll
  for (int pi = 0; pi < 2; ++pi) {
    const int qt = pi ? (15 - (int)blockIdx.y) : (int)blockIdx.y;
    const int nT = 2 * qt + 2;

    // Q fragments in registers
    f16x8 aq[4];
    {
      size_t qrow = base + (size_t)(qt * 128 + w * 16 + lr) * 2048;
      #pragma unroll
      for (int ks = 0; ks < 4; ++ks)
        aq[ks] = *reinterpret_cast<const f16x8*>(qv + qrow + ks * 32 + lg * 8);
    }

    f32x4 accY[8];
    #pragma unroll
    for (int i = 0; i < 8; ++i) { f32x4 z = {0.f, 0.f, 0.f, 0.f}; accY[i] = z; }

    STAGE(0, 0);
    asm volatile("s_waitcnt vmcnt(0)" ::: "memory");
    __builtin_amdgcn_s_barrier();
    __builtin_amdgcn_sched_barrier(0);

    for (int t = 0; t < nT; ++t) {
      const int cur = t & 1;

      float nmv[4][4];                            // mask for tile t -- FIRST
      #pragma unroll
      for (int fm = 0; fm < 4; ++fm)
        #pragma unroll
        for (int r = 0; r < 4; ++r)
          nmv[fm][r] = nm[(size_t)(qt * 128 + w * 16 + lg * 4 + r) * 2048 +
                          t * 64 + fm * 16 + lr];
      __builtin_amdgcn_sched_barrier(0);          // pin: nm loads before DMA

      if (t + 1 < nT) STAGE(t + 1, cur ^ 1);      // DMA overlaps compute below

      // ---- S strip (16 x 64) = Q . K^T ----
      f32x4 accS[4];
      #pragma unroll
      for (int i = 0; i < 4; ++i) { f32x4 z = {0.f, 0.f, 0.f, 0.f}; accS[i] = z; }
      #pragma unroll
      for (int ks = 0; ks < 4; ++ks) {
        #pragma unroll
        for (int fm = 0; fm < 4; ++fm) {
          int br = fm * 16 + lr;
          f16x8 bk = *reinterpret_cast<const f16x8*>(
              (const char*)Ks[cur] + br * 256 + ((ks * 64 + lg * 16) ^ swzx(br)));
          accS[fm] = __builtin_amdgcn_mfma_f32_16x16x32_f16(aq[ks], bk, accS[fm], 0, 0, 0);
        }
      }

      // ---- mask-multiply fp32, park P (fp16, wave-private rows) ----
      #pragma unroll
      for (int fm = 0; fm < 4; ++fm)
        #pragma unroll
        for (int r = 0; r < 4; ++r) {
          float pv = accS[fm][r] * nmv[fm][r];
          int pr = w * 16 + lg * 4 + r, pc = fm * 16 + lr;
          *reinterpret_cast<_Float16*>((char*)Ps + pr * 128 + ((pc * 2) ^ swzx(pr))) =
              (_Float16)pv;
        }

      // ---- Y strip (16 x 128) += P . V ----
      #pragma unroll
      for (int ks = 0; ks < 2; ++ks) {
        int ar = w * 16 + lr;
        f16x8 ap = *reinterpret_cast<const f16x8*>(
            (const char*)Ps + ar * 128 + ((ks * 64 + lg * 16) ^ swzx(ar)));
        #pragma unroll
        for (int fv = 0; fv < 8; ++fv) {
          int br = fv * 16 + lr;
          f16x8 bv = *reinterpret_cast<const f16x8*>(
              (const char*)Vs[cur] + br * 128 + ((ks * 64 + lg * 16) ^ swzx(br)));
          accY[fv] = __builtin_amdgcn_mfma_f32_16x16x32_f16(ap, bv, accY[fv], 0, 0, 0);
        }
      }

      // next tile's DMA landed (overlapped); sync all waves
      asm volatile("s_waitcnt vmcnt(0)" ::: "memory");
      __builtin_amdgcn_s_barrier();
      __builtin_amdgcn_sched_barrier(0);
    }

    // epilogue: RMSNorm over V=128 per row, write y fp16 (b,n,h,v)
    #pragma unroll
    for (int r = 0; r < 4; ++r) {
      float sq = 0.f;
      #pragma unroll
      for (int fv = 0; fv < 8; ++fv) { float yy = accY[fv][r]; sq += yy * yy; }
      sq += __shfl_xor(sq, 1); sq += __shfl_xor(sq, 2);
      sq += __shfl_xor(sq, 4); sq += __shfl_xor(sq, 8);
      float scale = rsqrtf(sq * (1.0f / 128.0f) + 1e-6f);
      int nrow = qt * 128 + w * 16 + lg * 4 + r;
      size_t orow = ((size_t)b * 2048 + nrow) * 2048 + (size_t)h * 128;
      #pragma unroll
      for (int fv = 0; fv < 8; ++fv) {
        int col = fv * 16 + lr;
        y[orow + col] = (_Float16)(accY[fv][r] * scale * rms_scale[col]);
      }
    }
  }
}

extern "C" void kernel_launch(void* const* d_in, const int* in_sizes, int n_in,
                              void* d_out, int out_size, void* d_ws, size_t ws_size,
                              hipStream_t stream) {
  (void)in_sizes; (void)n_in; (void)out_size; (void)ws_size;
  const float* x  = (const float*)d_in[0];
  const float* nm = (const float*)d_in[1];
  const float* wq = (const float*)d_in[2];
  const float* wk = (const float*)d_in[3];
  const float* wv = (const float*)d_in[4];
  const float* rs = (const float*)d_in[5];
  const float* wo = (const float*)d_in[6];

  _Float16* p = (_Float16*)d_ws;                 // ~92 MB of fp16 planes
  _Float16* xf  = p; p += 8388608;               // x fp16; reused as y after attn
  _Float16* wt  = p; p += 4194304;               // transposed weight (reused x4)
  _Float16* qf  = p; p += 8388608;
  _Float16* kf  = p; p += 8388608;
  _Float16* vf  = p; p += 8388608;
  _Float16* vtf = p; p += 8388608;               // v^T (b*h, v, n)

  k_cast_h<<<dim3(2048), dim3(256), 0, stream>>>(x, xf, 8388608);

  k_transpose_h<<<dim3(64, 64), dim3(32, 8), 0, stream>>>(wq, wt);
  k_gemm1<0><<<dim3(16, 32), dim3(256), 0, stream>>>(xf, wt, qf);
  k_transpose_h<<<dim3(64, 64), dim3(32, 8), 0, stream>>>(wk, wt);
  k_gemm1<0><<<dim3(16, 32), dim3(256), 0, stream>>>(xf, wt, kf);
  k_transpose_h<<<dim3(64, 64), dim3(32, 8), 0, stream>>>(wv, wt);
  k_gemm1<0><<<dim3(16, 32), dim3(256), 0, stream>>>(xf, wt, vf);
  k_transpose_v<<<dim3(4, 64, 32), dim3(32, 8), 0, stream>>>(vf, vtf);
  k_transpose_h<<<dim3(64, 64), dim3(32, 8), 0, stream>>>(wo, wt);

  // y written into the (now dead) x plane
  k_attn1<<<dim3(32, 8), dim3(512), 0, stream>>>(qf, kf, vtf, nm, rs, xf);

  k_gemm1<1><<<dim3(16, 32), dim3(256), 0, stream>>>(xf, wt, d_out);
}

// Round 9
// 283.880 us; speedup vs baseline: 2.9600x; 1.0532x over previous
//
#include <hip/hip_runtime.h>
#include <hip/hip_bf16.h>

// TransNormer: causal linear attention, B=2 N=2048 D=2048 H=16 I=1 K=V=128.
// Precision: all tensors single-plane fp16, 1-pass mfma_f32_16x16x32_f16,
// fp32 accumulation (R8 measured absmax 0.03125 vs threshold 0.109).
// R9: attn -> 4-wave blocks, QBLK=64, grid (32,16) paired {j,31-j} (uniform 33
// tile-units, 512 blocks = 2 blocks/CU co-resident; 72KB LDS) + setprio around
// MFMA. Projection GEMMs merged into one N=6144 dispatch.

typedef _Float16 f16x8 __attribute__((ext_vector_type(8)));
typedef _Float16 f16x4 __attribute__((ext_vector_type(4)));
typedef float    f32x4 __attribute__((ext_vector_type(4)));

#define DEV static __device__ __forceinline__

// XOR swizzle of byte bits 4-6 (bank-group spread); 16B blocks are atomic.
DEV int swzx(int row) { return (((row & 7) ^ ((row >> 3) & 7)) << 4); }

typedef const unsigned int __attribute__((address_space(1)))* gas_t;
typedef unsigned int __attribute__((address_space(3)))* las_t;
DEV void gld16(const void* g, void* l) {   // global -> LDS DMA, 16B/lane
  __builtin_amdgcn_global_load_lds((gas_t)g, (las_t)l, 16, 0, 0);
}

// ---------------- cast fp32 -> fp16, contiguous ----------------
__global__ void k_cast_h(const float* __restrict__ in, _Float16* __restrict__ out, int n) {
  int i = (blockIdx.x * blockDim.x + threadIdx.x) * 4;
  int stride = gridDim.x * blockDim.x * 4;
  for (; i < n; i += stride) {
    float4 v = *reinterpret_cast<const float4*>(in + i);
    f16x4 o;
    o[0] = (_Float16)v.x; o[1] = (_Float16)v.y;
    o[2] = (_Float16)v.z; o[3] = (_Float16)v.w;
    *reinterpret_cast<f16x4*>(out + i) = o;
  }
}

// ------- transpose + cast: out[c][r] = fp16(in[r][c]), 2048x2048 -------
__global__ void k_transpose_h(const float* __restrict__ in, _Float16* __restrict__ out) {
  __shared__ float tile[32][33];
  int tx = threadIdx.x, ty = threadIdx.y;           // block (32,8)
  int c0 = blockIdx.x * 32, r0 = blockIdx.y * 32;
  #pragma unroll
  for (int j = 0; j < 4; ++j)
    tile[ty + j * 8][tx] = in[(size_t)(r0 + ty + j * 8) * 2048 + c0 + tx];
  __syncthreads();
  #pragma unroll
  for (int j = 0; j < 4; ++j)
    out[(size_t)(c0 + ty + j * 8) * 2048 + r0 + tx] = (_Float16)tile[tx][ty + j * 8];
}

// --- batched transpose: v = qkv[:, 4096+h*128 .. ] (stride 6144) -> (bh,v,n) ---
__global__ void k_transpose_v(const _Float16* __restrict__ in, _Float16* __restrict__ out) {
  __shared__ _Float16 tile[32][33];
  int tx = threadIdx.x, ty = threadIdx.y;           // block (32,8)
  int v0 = blockIdx.x * 32, n0 = blockIdx.y * 32, bh = blockIdx.z;
  int b = bh >> 4, h = bh & 15;
  #pragma unroll
  for (int j = 0; j < 4; ++j)
    tile[ty + j * 8][tx] =
        in[(size_t)(b * 2048 + n0 + ty + j * 8) * 6144 + 4096 + h * 128 + v0 + tx];
  __syncthreads();
  #pragma unroll
  for (int j = 0; j < 4; ++j)
    out[((size_t)bh * 128 + v0 + ty + j * 8) * 2048 + n0 + tx] = tile[tx][ty + j * 8];
}

// ---- GEMM: C[4096][Nt*128] = A[4096][2048] * B[Nt*128][2048]^T, fp16 1-pass --
// 128x128 tile, BK=64, 4 waves, global_load_lds staging (pre-swizzled source,
// linear dest), 32KB LDS. OUTF32: 1 -> fp32 C (d_out), 0 -> fp16 C. ldc = C row
// stride (6144 merged qkv, 2048 final).
template <int OUTF32>
__global__ __launch_bounds__(256) void k_gemm1(const _Float16* __restrict__ A,
                                               const _Float16* __restrict__ B,
                                               void* __restrict__ C, int ldc) {
  __shared__ __align__(16) _Float16 As[128 * 64];
  __shared__ __align__(16) _Float16 Bs[128 * 64];
  const int tid = threadIdx.x;
  const int lane = tid & 63, w = tid >> 6;
  const int lr = lane & 15, lg = lane >> 4;
  const int bm = blockIdx.y, bn = blockIdx.x;
  const int wr = (w >> 1) * 64, wc = (w & 1) * 64;

  f32x4 acc[4][4];
  #pragma unroll
  for (int i = 0; i < 4; ++i)
    #pragma unroll
    for (int j = 0; j < 4; ++j) { f32x4 z = {0.f, 0.f, 0.f, 0.f}; acc[i][j] = z; }

  const size_t aOff = (size_t)(bm * 128) * 2048;
  const size_t bOff = (size_t)(bn * 128) * 2048;

  for (int kt = 0; kt < 32; ++kt) {
    __syncthreads();                               // prev readers done
    #pragma unroll
    for (int it = 0; it < 4; ++it) {               // 16B/lane DMA, lane-linear dest
      int row = it * 32 + (tid >> 3);
      int cb  = ((tid & 7) * 16) ^ swzx(row);      // pre-swizzled source col (bytes)
      size_t g = (size_t)row * 2048 + kt * 64 + (cb >> 1);
      int ld = it * 4096 + tid * 16;               // bytes: 32 rows x 128 B per it
      gld16(A + aOff + g, (char*)As + ld);
      gld16(B + bOff + g, (char*)Bs + ld);
    }
    __syncthreads();                               // drains vmcnt(0): DMA landed
    #pragma unroll
    for (int ks = 0; ks < 2; ++ks) {
      f16x8 af[4], bf[4];
      #pragma unroll
      for (int f = 0; f < 4; ++f) {
        int ar = wr + f * 16 + lr;
        af[f] = *reinterpret_cast<const f16x8*>((const char*)As + ar * 128 +
                                                ((ks * 64 + lg * 16) ^ swzx(ar)));
        int br = wc + f * 16 + lr;
        bf[f] = *reinterpret_cast<const f16x8*>((const char*)Bs + br * 128 +
                                                ((ks * 64 + lg * 16) ^ swzx(br)));
      }
      __builtin_amdgcn_s_setprio(1);
      #pragma unroll
      for (int i = 0; i < 4; ++i)
        #pragma unroll
        for (int j = 0; j < 4; ++j)
          acc[i][j] = __builtin_amdgcn_mfma_f32_16x16x32_f16(af[i], bf[j], acc[i][j], 0, 0, 0);
      __builtin_amdgcn_s_setprio(0);
    }
  }

  #pragma unroll
  for (int fm = 0; fm < 4; ++fm)
    #pragma unroll
    for (int fn = 0; fn < 4; ++fn)
      #pragma unroll
      for (int r = 0; r < 4; ++r) {
        int grow = bm * 128 + wr + fm * 16 + lg * 4 + r;   // D row = (lane>>4)*4+r
        int gcol = bn * 128 + wc + fn * 16 + lr;           // D col = lane&15
        float v = acc[fm][fn][r];
        size_t o = (size_t)grow * ldc + gcol;
        if (OUTF32) ((float*)C)[o] = v;
        else        ((_Float16*)C)[o] = (_Float16)v;
      }
}

// ---------------- fused masked attention + RMSNorm, fp16 1-pass ----------
// 4 waves (256 thr), QBLK=64, KVBLK=64. grid (32, 16): block j does q-tiles
// {j, 31-j} -> uniform 33 KV-tile-units; 512 blocks = 2/CU co-resident.
// K, V^T DMA-staged into double-buffered LDS (72KB); P fp16 plane (wave-
// private rows). Q/K read from merged qkv buffer (row stride 6144).
__global__ __launch_bounds__(256) void k_attn1(const _Float16* __restrict__ qkv,
                                               const _Float16* __restrict__ vt,
                                               const float* __restrict__ nm,
                                               const float* __restrict__ rms_scale,
                                               _Float16* __restrict__ y) {
  __shared__ __align__(16) _Float16 Ks[2][64 * 128];   // [m][k] 16KB x2
  __shared__ __align__(16) _Float16 Vs[2][128 * 64];   // [v][m] 16KB x2
  __shared__ __align__(16) _Float16 Ps[64 * 64];       // [n][m] 8KB
  const int tid = threadIdx.x;
  const int lane = tid & 63, w = tid >> 6;             // w in 0..3
  const int lr = lane & 15, lg = lane >> 4;
  const int bh = blockIdx.x, b = bh >> 4, h = bh & 15;
  const _Float16* qb = qkv + (size_t)b * 2048 * 6144 + h * 128;          // q cols
  const _Float16* kb = qkv + (size_t)b * 2048 * 6144 + 2048 + h * 128;   // k cols
  const size_t vbase = (size_t)bh * 128 * 2048;                          // (bh,v,n)

  const int krow = tid >> 4, kc = tid & 15;    // K stage: 16 rows/it, 16 chunks
  const int vrow = tid >> 3, vc = tid & 7;     // V stage: 32 rows/it, 8 chunks

  auto STAGE = [&](int t, int bufi) {
    #pragma unroll
    for (int it = 0; it < 4; ++it) {
      int kr = it * 16 + krow;
      int gk = ((kc * 16) ^ swzx(kr)) >> 1;
      gld16(kb + (size_t)(t * 64 + kr) * 6144 + gk,
            (char*)Ks[bufi] + it * 4096 + tid * 16);   // 16 rows x 256 B per it
      int vr = it * 32 + vrow;
      int gv = ((vc * 16) ^ swzx(vr)) >> 1;
      gld16(vt + vbase + (size_t)vr * 2048 + t * 64 + gv,
            (char*)Vs[bufi] + it * 4096 + tid * 16);   // 32 rows x 128 B per it
    }
  };

  #pragma unroll
  for (int pi = 0; pi < 2; ++pi) {
    const int qt = pi ? (31 - (int)blockIdx.y) : (int)blockIdx.y;  // 64-row q-tile
    const int nT = qt + 1;

    // Q fragments in registers: rows qt*64 + w*16 + lr
    f16x8 aq[4];
    {
      const _Float16* qrow = qb + (size_t)(qt * 64 + w * 16 + lr) * 6144;
      #pragma unroll
      for (int ks = 0; ks < 4; ++ks)
        aq[ks] = *reinterpret_cast<const f16x8*>(qrow + ks * 32 + lg * 8);
    }

    f32x4 accY[8];
    #pragma unroll
    for (int i = 0; i < 8; ++i) { f32x4 z = {0.f, 0.f, 0.f, 0.f}; accY[i] = z; }

    STAGE(0, 0);
    asm volatile("s_waitcnt vmcnt(0)" ::: "memory");
    __builtin_amdgcn_s_barrier();
    __builtin_amdgcn_sched_barrier(0);

    for (int t = 0; t < nT; ++t) {
      const int cur = t & 1;

      float nmv[4][4];                            // mask for tile t -- FIRST
      #pragma unroll
      for (int fm = 0; fm < 4; ++fm)
        #pragma unroll
        for (int r = 0; r < 4; ++r)
          nmv[fm][r] = nm[(size_t)(qt * 64 + w * 16 + lg * 4 + r) * 2048 +
                          t * 64 + fm * 16 + lr];
      __builtin_amdgcn_sched_barrier(0);          // pin: nm loads before DMA

      if (t + 1 < nT) STAGE(t + 1, cur ^ 1);      // DMA overlaps compute below

      // ---- S strip (16 x 64) = Q . K^T ----
      f32x4 accS[4];
      #pragma unroll
      for (int i = 0; i < 4; ++i) { f32x4 z = {0.f, 0.f, 0.f, 0.f}; accS[i] = z; }
      __builtin_amdgcn_s_setprio(1);
      #pragma unroll
      for (int ks = 0; ks < 4; ++ks) {
        #pragma unroll
        for (int fm = 0; fm < 4; ++fm) {
          int br = fm * 16 + lr;
          f16x8 bk = *reinterpret_cast<const f16x8*>(
              (const char*)Ks[cur] + br * 256 + ((ks * 64 + lg * 16) ^ swzx(br)));
          accS[fm] = __builtin_amdgcn_mfma_f32_16x16x32_f16(aq[ks], bk, accS[fm], 0, 0, 0);
        }
      }
      __builtin_amdgcn_s_setprio(0);

      // ---- mask-multiply fp32, park P (fp16, wave-private rows) ----
      #pragma unroll
      for (int fm = 0; fm < 4; ++fm)
        #pragma unroll
        for (int r = 0; r < 4; ++r) {
          float pv = accS[fm][r] * nmv[fm][r];
          int pr = w * 16 + lg * 4 + r, pc = fm * 16 + lr;
          *reinterpret_cast<_Float16*>((char*)Ps + pr * 128 + ((pc * 2) ^ swzx(pr))) =
              (_Float16)pv;
        }

      // ---- Y strip (16 x 128) += P . V ----
      __builtin_amdgcn_s_setprio(1);
      #pragma unroll
      for (int ks = 0; ks < 2; ++ks) {
        int ar = w * 16 + lr;
        f16x8 ap = *reinterpret_cast<const f16x8*>(
            (const char*)Ps + ar * 128 + ((ks * 64 + lg * 16) ^ swzx(ar)));
        #pragma unroll
        for (int fv = 0; fv < 8; ++fv) {
          int br = fv * 16 + lr;
          f16x8 bv = *reinterpret_cast<const f16x8*>(
              (const char*)Vs[cur] + br * 128 + ((ks * 64 + lg * 16) ^ swzx(br)));
          accY[fv] = __builtin_amdgcn_mfma_f32_16x16x32_f16(ap, bv, accY[fv], 0, 0, 0);
        }
      }
      __builtin_amdgcn_s_setprio(0);

      // next tile's DMA landed (overlapped); sync all waves
      asm volatile("s_waitcnt vmcnt(0)" ::: "memory");
      __builtin_amdgcn_s_barrier();
      __builtin_amdgcn_sched_barrier(0);
    }

    // epilogue: RMSNorm over V=128 per row, write y fp16 (b,n,h,v)
    #pragma unroll
    for (int r = 0; r < 4; ++r) {
      float sq = 0.f;
      #pragma unroll
      for (int fv = 0; fv < 8; ++fv) { float yy = accY[fv][r]; sq += yy * yy; }
      sq += __shfl_xor(sq, 1); sq += __shfl_xor(sq, 2);
      sq += __shfl_xor(sq, 4); sq += __shfl_xor(sq, 8);
      float scale = rsqrtf(sq * (1.0f / 128.0f) + 1e-6f);
      int nrow = qt * 64 + w * 16 + lg * 4 + r;
      size_t orow = ((size_t)b * 2048 + nrow) * 2048 + (size_t)h * 128;
      #pragma unroll
      for (int fv = 0; fv < 8; ++fv) {
        int col = fv * 16 + lr;
        y[orow + col] = (_Float16)(accY[fv][r] * scale * rms_scale[col]);
      }
    }
  }
}

extern "C" void kernel_launch(void* const* d_in, const int* in_sizes, int n_in,
                              void* d_out, int out_size, void* d_ws, size_t ws_size,
                              hipStream_t stream) {
  (void)in_sizes; (void)n_in; (void)out_size; (void)ws_size;
  const float* x  = (const float*)d_in[0];
  const float* nm = (const float*)d_in[1];
  const float* wq = (const float*)d_in[2];
  const float* wk = (const float*)d_in[3];
  const float* wv = (const float*)d_in[4];
  const float* rs = (const float*)d_in[5];
  const float* wo = (const float*)d_in[6];

  _Float16* p = (_Float16*)d_ws;                 // ~118 MB of fp16 planes
  _Float16* xf  = p; p += 8388608;               // x fp16; reused as y after attn
  _Float16* wt3 = p; p += 12582912;              // [wqT; wkT; wvT] (6144 x 2048)
  _Float16* wto = p; p += 4194304;               // woT
  _Float16* qkv = p; p += 25165824;              // (b,n) x (q|k|v) (4096 x 6144)
  _Float16* vtf = p; p += 8388608;               // v^T (b*h, v, n)

  k_cast_h<<<dim3(2048), dim3(256), 0, stream>>>(x, xf, 8388608);

  k_transpose_h<<<dim3(64, 64), dim3(32, 8), 0, stream>>>(wq, wt3);
  k_transpose_h<<<dim3(64, 64), dim3(32, 8), 0, stream>>>(wk, wt3 + 4194304);
  k_transpose_h<<<dim3(64, 64), dim3(32, 8), 0, stream>>>(wv, wt3 + 8388608);
  k_transpose_h<<<dim3(64, 64), dim3(32, 8), 0, stream>>>(wo, wto);

  // merged q|k|v projection: C (4096 x 6144), row stride 6144
  k_gemm1<0><<<dim3(48, 32), dim3(256), 0, stream>>>(xf, wt3, qkv, 6144);
  k_transpose_v<<<dim3(4, 64, 32), dim3(32, 8), 0, stream>>>(qkv, vtf);

  // y written into the (now dead) x plane
  k_attn1<<<dim3(32, 16), dim3(256), 0, stream>>>(qkv, vtf, nm, rs, xf);

  k_gemm1<1><<<dim3(16, 32), dim3(256), 0, stream>>>(xf, wto, d_out, 2048);
}